// Round 16
// baseline (17754.097 us; speedup 1.0000x reference)
//
#include <hip/hip_runtime.h>
#include <stdint.h>

#define LNUM 16
#define TT 64
#define NCLSN 30
#define EPSF 1e-6f
#define NBUF 8

typedef _Float16 half2v __attribute__((ext_vector_type(2)));

__device__ inline float fdot2(uint32_t a, uint32_t b, float c) {
  return __builtin_amdgcn_fdot2(__builtin_bit_cast(half2v, a),
                                __builtin_bit_cast(half2v, b), c, false);
}
__device__ inline float dot8(uint4 w, uint4 xv, float a) {
  a = fdot2(w.x, xv.x, a); a = fdot2(w.y, xv.y, a);
  a = fdot2(w.z, xv.z, a); a = fdot2(w.w, xv.w, a);
  return a;
}
__device__ __forceinline__ float rcpf(float x) { return __builtin_amdgcn_rcpf(x); }
__device__ inline float sigf(float x) { return rcpf(1.0f + __expf(-x)); }
__device__ __forceinline__ float tanh_fast(float x) {
  float xc = fminf(fmaxf(x, -15.f), 15.f);
  float e = __expf(2.f * xc);
  return (e - 1.f) * rcpf(e + 1.f);
}
__device__ __forceinline__ float softplus_fast(float x) {
  return fmaxf(x, 0.f) + __logf(1.f + __expf(-fabsf(x)));
}
__device__ inline uint32_t packh2(float a, float b) {
  half2v h; h.x = (_Float16)a; h.y = (_Float16)b;
  return __builtin_bit_cast(uint32_t, h);
}
__device__ inline uint16_t f16bits(float a) {
  _Float16 h = (_Float16)a;
  return __builtin_bit_cast(uint16_t, h);
}
__device__ __forceinline__ void gl_lds16(const uint4* g, uint4* l) {
  __builtin_amdgcn_global_load_lds(
      (const __attribute__((address_space(1))) void*)g,
      (__attribute__((address_space(3))) void*)l, 16, 0, 0);
}
__device__ __forceinline__ void bar_lgkm() {
  asm volatile("s_waitcnt lgkmcnt(0)\ns_barrier" ::: "memory");
}

// ---------- prep WR[lc][i][896]: tid<896 -> row=tid>>1, s=tid&1; chunk = s?17+i:i;
// s==1,i==16 is the BIAS chunk: (bias_comb, 0 x7) dotted against (1,0,...,0) ----------
__global__ void prepWR(const float* __restrict__ W_ih, const float* __restrict__ W_hh,
                       const float* __restrict__ b_ih, const float* __restrict__ b_hh,
                       uint4* __restrict__ WR) {
  int idx = blockIdx.x * 256 + threadIdx.x;   // < 32*17*896 = 487424
  if (idx >= 487424) return;
  int tid = idx % 896;
  int rem = idx / 896;
  int i = rem % 17;
  int lc = rem / 17;
  int r = tid >> 1, s = tid & 1;
  uint32_t p0 = 0, p1 = 0, p2 = 0, p3 = 0;
  if (s == 1 && i == 16) {
    float b = b_ih[(size_t)lc * 512 + r] + b_hh[(size_t)lc * 512 + r];
    p0 = packh2(b, 0.f);
  } else {
    int c = s ? 17 + i : i;
    bool zero = ((lc & 1) != 0) && (c == 16);
    if (!zero) {
      float w[8];
#pragma unroll
      for (int e = 0; e < 8; e++) {
        int k = 8 * c + e;
        w[e] = (k < 136) ? W_ih[((size_t)lc * 512 + r) * 136 + k]
                         : W_hh[((size_t)lc * 512 + r) * 128 + (k - 136)];
      }
      p0 = packh2(w[0], w[1]); p1 = packh2(w[2], w[3]);
      p2 = packh2(w[4], w[5]); p3 = packh2(w[6], w[7]);
    }
  }
  uint4 v; v.x = p0; v.y = p1; v.z = p2; v.w = p3;
  WR[idx] = v;
}

// ---------- prep WC[lc][c][64]: rows 448..511 full-K; c=0..32 chunks, c=33 bias ----------
__global__ void prepWC(const float* __restrict__ W_ih, const float* __restrict__ W_hh,
                       const float* __restrict__ b_ih, const float* __restrict__ b_hh,
                       uint4* __restrict__ WC) {
  int idx = blockIdx.x * 256 + threadIdx.x;   // < 32*34*64 = 69632
  if (idx >= 69632) return;
  int k = idx % 64;
  int rem = idx / 64;
  int c = rem % 34;
  int lc = rem / 34;
  int r = 448 + k;
  uint32_t p0 = 0, p1 = 0, p2 = 0, p3 = 0;
  if (c == 33) {
    float b = b_ih[(size_t)lc * 512 + r] + b_hh[(size_t)lc * 512 + r];
    p0 = packh2(b, 0.f);
  } else {
    bool zero = ((lc & 1) != 0) && (c == 16);
    if (!zero) {
      float w[8];
#pragma unroll
      for (int e = 0; e < 8; e++) {
        int kk = 8 * c + e;
        w[e] = (kk < 136) ? W_ih[((size_t)lc * 512 + r) * 136 + kk]
                          : W_hh[((size_t)lc * 512 + r) * 128 + (kk - 136)];
      }
      p0 = packh2(w[0], w[1]); p1 = packh2(w[2], w[3]);
      p2 = packh2(w[4], w[5]); p3 = packh2(w[6], w[7]);
    }
  }
  uint4 v; v.x = p0; v.y = p1; v.z = p2; v.w = p3;
  WC[idx] = v;
}

__global__ void prepB(const float* __restrict__ W_if, const float* __restrict__ W_fri,
                      const float* __restrict__ W_c1, const float* __restrict__ W_c2,
                      uint32_t* __restrict__ Wif16, float* __restrict__ WfriT,
                      float* __restrict__ Wc1T, float* __restrict__ Wc2T) {
  int idx = blockIdx.x * 256 + threadIdx.x;
  if (idx < 2560)  {
    int j = idx / 64, k2 = idx % 64;
    Wif16[idx] = packh2(W_if[j * 128 + 2 * k2], W_if[j * 128 + 2 * k2 + 1]);
    return;
  }
  idx -= 2560;
  if (idx < 81920) { int k = idx / 128, j = idx % 128; WfriT[idx] = W_fri[j * 640 + k]; return; }
  idx -= 81920;
  if (idx < 32768) { int k = idx / 128, j = idx % 128; Wc1T[idx]  = W_c1[j * 256 + k]; return; }
  idx -= 32768;
  if (idx < 3840)  { int k = idx / 30,  j = idx % 30;  Wc2T[idx]  = W_c2[j * 128 + k]; return; }
}

// ---------- DNC memory step, 8 lanes (lane = m); state in registers ----------
__device__ __forceinline__ void memstep_par(
    int m, const float* __restrict__ xi,
    float (&mm)[8], float (&lkr)[8],
    float& u, float& p, float& r, float& w,
    float (&rv)[8]) {
  float rk[8], wk[8], er[8], wv[8];
#pragma unroll
  for (int c = 0; c < 8; c++) {
    rk[c] = tanh_fast(xi[c]);
    wk[c] = tanh_fast(xi[9 + c]);
    er[c] = sigf(xi[18 + c]);
    wv[c] = tanh_fast(xi[26 + c]);
  }
  float rs  = softplus_fast(xi[8]);
  float wsd = softplus_fast(xi[17]);
  float fg  = sigf(xi[34]), ag = sigf(xi[35]), wg = sigf(xi[36]);
  float l0 = xi[37], l1 = xi[38], l2 = xi[39];
  float lmx = fmaxf(l0, fmaxf(l1, l2));
  float eb = __expf(l0 - lmx), ef = __expf(l1 - lmx), ec = __expf(l2 - lmx);
  float minv = rcpf(eb + ef + ec);
  float mode_b = eb * minv, mode_f = ef * minv, mode_c = ec * minv;

  u = u + (1.f - u) * w;
  u *= (1.f - fg * r);

  float kn2 = 0.f, mn2 = 0.f, dp = 0.f;
#pragma unroll
  for (int c = 0; c < 8; c++) { kn2 += wk[c]*wk[c]; mn2 += mm[c]*mm[c]; dp += wk[c]*mm[c]; }
  float sim = dp * rcpf((sqrtf(kn2) + EPSF) * (sqrtf(mn2) + EPSF)) * wsd;
  float mx = sim;
  mx = fmaxf(mx, __shfl_xor(mx, 1));
  mx = fmaxf(mx, __shfl_xor(mx, 2));
  mx = fmaxf(mx, __shfl_xor(mx, 4));
  float e = __expf(sim - mx);
  float se = e;
  se += __shfl_xor(se, 1); se += __shfl_xor(se, 2); se += __shfl_xor(se, 4);
  float wcw = e * rcpf(se);

  float up = EPSF + (1.f - EPSF) * u;
  float prod = 1.f;
#pragma unroll
  for (int n = 0; n < 8; n++) {
    float un = __shfl(up, n);
    bool before = (un < up) || (un == up && n < m);
    prod *= ((n != m) && before) ? un : 1.f;
  }
  float alloc = (1.f - up) * prod;
  float wn = wg * (ag * alloc + (1.f - ag) * wcw);
  float sw = wn;
  sw += __shfl_xor(sw, 1); sw += __shfl_xor(sw, 2); sw += __shfl_xor(sw, 4);

#pragma unroll
  for (int c = 0; c < 8; c++)
    mm[c] = mm[c] * (1.f - wn * er[c]) + wn * wv[c];

  float wnv[8], pvv[8];
#pragma unroll
  for (int n = 0; n < 8; n++) { wnv[n] = __shfl(wn, n); pvv[n] = __shfl(p, n); }
#pragma unroll
  for (int jj = 0; jj < 8; jj++)
    lkr[jj] = (jj == m) ? 0.f : ((1.f - wn - wnv[jj]) * lkr[jj] + wn * pvv[jj]);
  p = (1.f - sw) * p + wn;

  float rn2 = 0.f; mn2 = 0.f; dp = 0.f;
#pragma unroll
  for (int c = 0; c < 8; c++) { rn2 += rk[c]*rk[c]; mn2 += mm[c]*mm[c]; dp += rk[c]*mm[c]; }
  float sim2 = dp * rcpf((sqrtf(rn2) + EPSF) * (sqrtf(mn2) + EPSF)) * rs;
  float mx2 = sim2;
  mx2 = fmaxf(mx2, __shfl_xor(mx2, 1));
  mx2 = fmaxf(mx2, __shfl_xor(mx2, 2));
  mx2 = fmaxf(mx2, __shfl_xor(mx2, 4));
  float e2 = __expf(sim2 - mx2);
  float se2 = e2;
  se2 += __shfl_xor(se2, 1); se2 += __shfl_xor(se2, 2); se2 += __shfl_xor(se2, 4);
  float cw = e2 * rcpf(se2);

  float rv8[8];
#pragma unroll
  for (int n = 0; n < 8; n++) rv8[n] = __shfl(r, n);
  float fwd = 0.f;
#pragma unroll
  for (int jj = 0; jj < 8; jj++) fwd += lkr[jj] * rv8[jj];
  float bw[8];
#pragma unroll
  for (int jj = 0; jj < 8; jj++) bw[jj] = r * lkr[jj];
#pragma unroll
  for (int jj = 0; jj < 8; jj++) {
    bw[jj] += __shfl_xor(bw[jj], 1);
    bw[jj] += __shfl_xor(bw[jj], 2);
    bw[jj] += __shfl_xor(bw[jj], 4);
  }
  bool s1 = (m & 1) != 0, s2 = (m & 2) != 0, s4 = (m & 4) != 0;
  float t0 = s1 ? bw[1] : bw[0];
  float t1 = s1 ? bw[3] : bw[2];
  float t2 = s1 ? bw[5] : bw[4];
  float t3 = s1 ? bw[7] : bw[6];
  float q0 = s2 ? t1 : t0;
  float q1 = s2 ? t3 : t2;
  float bwd = s4 ? q1 : q0;

  float rn = mode_c * cw + mode_f * fwd + mode_b * bwd;

#pragma unroll
  for (int c = 0; c < 8; c++) rv[c] = rn * mm[c];
#pragma unroll
  for (int c = 0; c < 8; c++) {
    rv[c] += __shfl_xor(rv[c], 1);
    rv[c] += __shfl_xor(rv[c], 2);
    rv[c] += __shfl_xor(rv[c], 4);
  }
  r = rn; w = wn;
}

// ---------- aux (wave 15): xi GEMV from LDS weights, then memstep ----------
__device__ __forceinline__ void aux_work(
    int lane, bool write_inp, float bifr,
    const uint4* __restrict__ wifu4,
    const uint4* __restrict__ outhu4, float* __restrict__ xi_lds,
    uint4* __restrict__ inpu4,
    float (&mm)[8], float (&lkr)[8],
    float& u, float& p, float& r, float& w,
    float (&rv)[8]) {
  if (lane < 40) {
    float acc0 = 0.f, acc1 = 0.f;
    const uint4* wr = wifu4 + lane * 16;
#pragma unroll
    for (int q = 0; q < 8; q++) {
      acc0 = dot8(wr[2 * q],     outhu4[2 * q],     acc0);
      acc1 = dot8(wr[2 * q + 1], outhu4[2 * q + 1], acc1);
    }
    xi_lds[lane] = acc0 + acc1 + bifr;
  }
  asm volatile("s_waitcnt lgkmcnt(0)" ::: "memory");
  __builtin_amdgcn_sched_barrier(0);
  __builtin_amdgcn_wave_barrier();
  if (lane < 8) {
    memstep_par(lane, xi_lds, mm, lkr, u, p, r, w, rv);
    if (write_inp && lane == 0) {
      uint4 pv4;
      pv4.x = packh2(rv[0], rv[1]); pv4.y = packh2(rv[2], rv[3]);
      pv4.z = packh2(rv[4], rv[5]); pv4.w = packh2(rv[6], rv[7]);
      inpu4[16] = pv4;
    }
  }
}

// ---------- main: 128 blocks x 1024 threads (14 staged GEMV waves, wave14 direct, wave15 aux) ----------
__global__ __launch_bounds__(1024) void dnc_main(
    const int* __restrict__ x, const float* __restrict__ embed,
    const uint4* __restrict__ WR, const uint4* __restrict__ WC,
    const uint32_t* __restrict__ Wif16, const float* __restrict__ b_if,
    const float* __restrict__ W_out, const float* __restrict__ b_out,
    float* __restrict__ y_buf) {
  __shared__ __align__(16) uint16_t hst[32 * 128];       // 8 KB
  __shared__ float c_st[32 * 128];                       // 16 KB
  __shared__ float gates_lds[512];                       // 2 KB
  __shared__ __align__(16) uint32_t wif_lds[2560];       // 10 KB
  __shared__ float emb_lds[495];
  __shared__ __align__(16) uint32_t inp16[17 * 4];
  __shared__ __align__(16) uint16_t outh16[128];
  __shared__ float inp_f32[128];
  __shared__ float xi_lds[40];
  __shared__ float rv_f32[8];
  __shared__ __align__(16) uint4 one1v;
  __shared__ __align__(16) uint4 sbuf[14 * NBUF * 64];   // 14 waves x 8 x 1KB = 112 KB

  uint4* inpu4 = (uint4*)inp16;
  uint4* hstu4 = (uint4*)hst;
  uint4* outhu4 = (uint4*)outh16;
  uint16_t* inpu16 = (uint16_t*)inp16;
  const uint4* wifu4 = (const uint4*)wif_lds;

  const int tid = threadIdx.x;
  const int b0 = blockIdx.x;
  const int wave = tid >> 6, lane = tid & 63;
  const bool isGW  = (wave < 14);    // staged GEMV (rows 0-447 paired)
  const bool isW14 = (wave == 14);   // rows 448-511 full-K direct
  const int r = tid >> 1, s = tid & 1;
  uint4* myslab = sbuf + (size_t)wave * (NBUF * 64);

  // aux state (wave 15)
  float mm[8] = {0.f,0.f,0.f,0.f,0.f,0.f,0.f,0.f};
  float lkr[8] = {0.f,0.f,0.f,0.f,0.f,0.f,0.f,0.f};
  float p_u = 0.f, p_p = 0.f, p_r = 0.f, p_w = 0.f;
  float rvout[8];
  float bifr = 0.f;
  if (wave == 15 && lane < 40) bifr = b_if[lane];

  for (int i = tid; i < 32 * 128; i += 1024) { hst[i] = 0; c_st[i] = 0.f; }
  for (int i = tid; i < 2560; i += 1024) wif_lds[i] = Wif16[i];
  for (int i = tid; i < 495; i += 1024) emb_lds[i] = embed[i];
  if (tid == 0) { uint4 v; v.x = packh2(1.f, 0.f); v.y = 0; v.z = 0; v.w = 0; one1v = v; }
  __syncthreads();
  if (tid < 17) {   // emb for t=0 (slot 16 = zeros)
    int q = tid;
    int ix = x[b0 * TT + 0];
    uint32_t e[8];
#pragma unroll
    for (int e2 = 0; e2 < 8; e2++) {
      int k0 = 8 * q + e2;
      ((float*)e)[e2] = (k0 < 15) ? emb_lds[ix * 15 + k0] : 0.f;   // temp reuse
    }
    float* ef = (float*)e;
    uint4 v;
    v.x = packh2(ef[0], ef[1]); v.y = packh2(ef[2], ef[3]);
    v.z = packh2(ef[4], ef[5]); v.w = packh2(ef[6], ef[7]);
    inpu4[q] = v;
  }
  __syncthreads();

  int base = 0;
  // prologue: stage planes 0..6 of cell 0
  if (isGW) {
#pragma unroll
    for (int p5 = 0; p5 < 7; p5++)
      gl_lds16(WR + (size_t)p5 * 896 + tid, myslab + (size_t)p5 * 64);
  }

  for (int t = 0; t < TT; ++t) {
    for (int l = 0; l < LNUM; ++l) {
      const int lc0 = l * 2, lc1 = l * 2 + 1;
      const int nlc0 = (l == 15) ? 0 : lc0 + 2;
      float acc = 0.f;
      uint4 wd = {};

      // ===== Phase A: GEMV0 =====
      if (isGW) {
#pragma unroll
        for (int q = 0; q < 17; q++) {
          asm volatile("s_waitcnt vmcnt(6)" ::: "memory");
          __builtin_amdgcn_sched_barrier(0);
          uint4 w = myslab[(size_t)((base + q) & 7) * 64 + lane];
          uint4 xv;
          if (s == 0) xv = (q < 16) ? inpu4[q] : inpu4[16];
          else        xv = (q < 16) ? hstu4[lc0 * 16 + q] : one1v;
          if (s == 0 && q == 16) wd = w;
          else acc = dot8(w, xv, acc);
          // stage plane q+7 of the stream (cur cell then next cell)
          const int pp = q + 7;
          const uint4* src = (pp <= 16)
              ? WR + ((size_t)lc0 * 17 + pp) * 896 + tid
              : WR + ((size_t)lc1 * 17 + (pp - 17)) * 896 + tid;
          gl_lds16(src, myslab + (size_t)((base + pp) & 7) * 64);
        }
      } else if (isW14) {
        const uint4* wc = WC + (size_t)lc0 * 34 * 64 + lane;
#pragma unroll
        for (int c = 0; c < 34; c++) {
          uint4 w = wc[c * 64];
          if (c == 16) { wd = w; continue; }    // rv chunk deferred
          uint4 xv;
          if (c < 16)      xv = inpu4[c];
          else if (c < 33) xv = hstu4[lc0 * 16 + (c - 17)];
          else             xv = one1v;          // bias chunk
          acc = dot8(w, xv, acc);
        }
      } else {  // wave 15: aux
        if (t > 0 || l > 0)
          aux_work(lane, /*write_inp=*/(l != 0), bifr, wifu4, outhu4,
                   xi_lds, inpu4, mm, lkr, p_u, p_p, p_r, p_w, rvout);
      }
      base = (base + 17) & 7;
      bar_lgkm();   // B1: rv visible

      // ===== Phase B0: rv-dot + pair reduce + gates write =====
      if (isGW) {
        if (s == 0) acc = dot8(wd, inpu4[16], acc);
        acc += __shfl_xor(acc, 1);
        if (s == 0) gates_lds[r] = acc;
      } else if (isW14) {
        acc = dot8(wd, inpu4[16], acc);
        gates_lds[448 + lane] = acc;
      }
      bar_lgkm();   // B1b: gates ready

      // ===== Phase B1: LSTM0 =====
      if (tid < 128) {
        float gi = gates_lds[tid], gf = gates_lds[128 + tid];
        float gg = gates_lds[256 + tid], go = gates_lds[384 + tid];
        int ci = lc0 * 128 + tid;
        float c2 = sigf(gf) * c_st[ci] + sigf(gi) * tanh_fast(gg);
        c_st[ci] = c2;
        hst[ci] = f16bits(sigf(go) * tanh_fast(c2));
      }
      bar_lgkm();   // B2: h0 ready

      // ===== Phase C: GEMV1 (no defer; bias chunk in-stream) =====
      float cacc = 0.f;
      if (isGW) {
#pragma unroll
        for (int q = 0; q < 17; q++) {
          asm volatile("s_waitcnt vmcnt(6)" ::: "memory");
          __builtin_amdgcn_sched_barrier(0);
          uint4 w = myslab[(size_t)((base + q) & 7) * 64 + lane];
          uint4 xv;
          if (s == 0) xv = (q < 16) ? hstu4[lc0 * 16 + q] : one1v;   // q16: zero weights
          else        xv = (q < 16) ? hstu4[lc1 * 16 + q] : one1v;   // q16: bias
          cacc = dot8(w, xv, cacc);
          const int pp = q + 7;
          const uint4* src = (pp <= 16)
              ? WR + ((size_t)lc1 * 17 + pp) * 896 + tid
              : WR + ((size_t)nlc0 * 17 + (pp - 17)) * 896 + tid;
          gl_lds16(src, myslab + (size_t)((base + pp) & 7) * 64);
        }
        cacc += __shfl_xor(cacc, 1);
        if (s == 0) gates_lds[r] = cacc;
      } else if (isW14) {
        const uint4* wc = WC + (size_t)lc1 * 34 * 64 + lane;
#pragma unroll
        for (int c = 0; c < 34; c++) {
          uint4 w = wc[c * 64];
          uint4 xv;
          if (c < 16)       xv = hstu4[lc0 * 16 + c];
          else if (c == 16) xv = one1v;                    // zero weights
          else if (c < 33)  xv = hstu4[lc1 * 16 + (c - 17)];
          else              xv = one1v;                    // bias
          cacc = dot8(w, xv, cacc);
        }
        gates_lds[448 + lane] = cacc;
      } else {  // wave 15: emb prefetch for t+1
        if (l == 15 && t < 63 && lane < 17) {
          int q = lane;
          int ix = x[b0 * TT + t + 1];
          float ef[8];
#pragma unroll
          for (int e2 = 0; e2 < 8; e2++) {
            int k0 = 8 * q + e2;
            ef[e2] = (k0 < 15) ? emb_lds[ix * 15 + k0] : 0.f;
          }
          uint4 v;
          v.x = packh2(ef[0], ef[1]); v.y = packh2(ef[2], ef[3]);
          v.z = packh2(ef[4], ef[5]); v.w = packh2(ef[6], ef[7]);
          inpu4[q] = v;
        }
      }
      base = (base + 17) & 7;
      bar_lgkm();   // B3: gates ready

      // ===== Phase C2: LSTM1 =====
      if (tid < 128) {
        float gi = gates_lds[tid], gf = gates_lds[128 + tid];
        float gg = gates_lds[256 + tid], go = gates_lds[384 + tid];
        int ci = lc1 * 128 + tid;
        float c2 = sigf(gf) * c_st[ci] + sigf(gi) * tanh_fast(gg);
        c_st[ci] = c2;
        float h2 = sigf(go) * tanh_fast(c2);   // |h2|<1 -> clip no-op
        hst[ci] = f16bits(h2);
        inp_f32[tid] = h2;
        outh16[tid] = f16bits(h2);
        if (l != 15) inpu16[tid] = f16bits(h2);
      }
      bar_lgkm();   // B4: h1/out ready
    }  // l
  }  // t

  // epilogue: final memstep (t=63,l=15), then y
  if (wave == 15) {
    aux_work(lane, /*write_inp=*/false, bifr, wifu4, outhu4,
             xi_lds, inpu4, mm, lkr, p_u, p_p, p_r, p_w, rvout);
    if (lane == 0) {
#pragma unroll
      for (int c = 0; c < 8; c++) rv_f32[c] = rvout[c];
    }
  }
  __syncthreads();
  if (tid < 128) {
    int i = tid;
    float a = b_out[i];
    for (int k = 0; k < 128; ++k) a += inp_f32[k] * W_out[i * 136 + k];
    for (int k = 0; k < 8; ++k)   a += rv_f32[k] * W_out[i * 136 + 128 + k];
    y_buf[b0 * 128 + i] = a;
  }
}

// ---------- output head: 128 blocks (one per batch) x 128 threads ----------
__global__ void head_kernel(const float* __restrict__ y_buf, const float* __restrict__ f,
                            const float* __restrict__ WfriT, const float* __restrict__ b_fri,
                            const float* __restrict__ Wc1T, const float* __restrict__ b_c1,
                            const float* __restrict__ Wc2T, const float* __restrict__ b_c2,
                            float* __restrict__ out) {
  __shared__ float fl[640], yl[128], fo[128], h1l[128];
  int b = blockIdx.x, j = threadIdx.x;
  for (int i = j; i < 640; i += 128) fl[i] = f[b * 640 + i];
  yl[j] = y_buf[b * 128 + j];
  __syncthreads();
  float a = b_fri[j];
  for (int k = 0; k < 640; ++k) a += fl[k] * WfriT[k * 128 + j];
  fo[j] = fmaxf(a, 0.f);
  __syncthreads();
  float a2 = b_c1[j];
  for (int k = 0; k < 128; ++k) a2 += yl[k] * Wc1T[k * 128 + j];
  for (int k = 0; k < 128; ++k) a2 += fo[k] * Wc1T[(128 + k) * 128 + j];
  h1l[j] = fmaxf(a2, 0.f);
  __syncthreads();
  if (j < NCLSN) {
    float a3 = b_c2[j];
    for (int k = 0; k < 128; ++k) a3 += h1l[k] * Wc2T[k * NCLSN + j];
    out[b * NCLSN + j] = a3;
  }
}

extern "C" void kernel_launch(void* const* d_in, const int* in_sizes, int n_in,
                              void* d_out, int out_size, void* d_ws, size_t ws_size,
                              hipStream_t stream) {
  const int*   x     = (const int*)d_in[0];
  const float* f     = (const float*)d_in[1];
  const float* embed = (const float*)d_in[2];
  const float* W_ih  = (const float*)d_in[3];
  const float* W_hh  = (const float*)d_in[4];
  const float* b_ih  = (const float*)d_in[5];
  const float* b_hh  = (const float*)d_in[6];
  const float* W_if  = (const float*)d_in[7];
  const float* b_if  = (const float*)d_in[8];
  const float* W_out = (const float*)d_in[9];
  const float* b_out = (const float*)d_in[10];
  const float* W_fri = (const float*)d_in[11];
  const float* b_fri = (const float*)d_in[12];
  const float* W_c1  = (const float*)d_in[13];
  const float* b_c1  = (const float*)d_in[14];
  const float* W_c2  = (const float*)d_in[15];
  const float* b_c2  = (const float*)d_in[16];

  uint8_t* ws = (uint8_t*)d_ws;
  uint4* WR        = (uint4*)(ws + 0);           // 487424*16 = 7,798,784 B
  uint4* WC        = (uint4*)(ws + 7798784);     // 69632*16 = 1,114,112 B
  uint32_t* Wif16  = (uint32_t*)(ws + 8912896);  // 10,240 B
  float* WfriT     = (float*)(ws + 8923136);     // 327,680 B
  float* Wc1T      = (float*)(ws + 9250816);     // 131,072 B
  float* Wc2T      = (float*)(ws + 9381888);     // 15,360 B
  float* y_buf     = (float*)(ws + 9397248);     // 65,536 B
  float* out       = (float*)d_out;

  prepWR<<<1904, 256, 0, stream>>>(W_ih, W_hh, b_ih, b_hh, WR);
  prepWC<<<272, 256, 0, stream>>>(W_ih, W_hh, b_ih, b_hh, WC);
  prepB<<<473, 256, 0, stream>>>(W_if, W_fri, W_c1, W_c2, Wif16, WfriT, Wc1T, Wc2T);
  dnc_main<<<128, 1024, 0, stream>>>(x, embed, WR, WC, Wif16, b_if,
                                     W_out, b_out, y_buf);
  head_kernel<<<128, 128, 0, stream>>>(y_buf, f, WfriT, b_fri, Wc1T, b_c1,
                                       Wc2T, b_c2, out);
}

// Round 17
// 10022.859 us; speedup vs baseline: 1.7714x; 1.7714x over previous
//
#include <hip/hip_runtime.h>
#include <stdint.h>

#define LNUM 16
#define H 128
#define TT 64
#define NCLSN 30
#define EPSF 1e-6f

typedef _Float16 half2v __attribute__((ext_vector_type(2)));

__device__ inline float fdot2(uint32_t a, uint32_t b, float c) {
  return __builtin_amdgcn_fdot2(__builtin_bit_cast(half2v, a),
                                __builtin_bit_cast(half2v, b), c, false);
}
__device__ inline float dot8(uint4 w, uint4 xv, float a) {
  a = fdot2(w.x, xv.x, a); a = fdot2(w.y, xv.y, a);
  a = fdot2(w.z, xv.z, a); a = fdot2(w.w, xv.w, a);
  return a;
}
__device__ __forceinline__ float rcpf(float x) { return __builtin_amdgcn_rcpf(x); }
__device__ inline float sigf(float x) { return rcpf(1.0f + __expf(-x)); }
__device__ __forceinline__ float tanh_fast(float x) {
  float xc = fminf(fmaxf(x, -15.f), 15.f);
  float e = __expf(2.f * xc);
  return (e - 1.f) * rcpf(e + 1.f);
}
__device__ __forceinline__ float softplus_fast(float x) {
  return fmaxf(x, 0.f) + __logf(1.f + __expf(-fabsf(x)));
}
__device__ inline uint32_t packh2(float a, float b) {
  half2v h; h.x = (_Float16)a; h.y = (_Float16)b;
  return __builtin_bit_cast(uint32_t, h);
}
__device__ inline uint16_t f16bits(float a) {
  _Float16 h = (_Float16)a;
  return __builtin_bit_cast(uint16_t, h);
}
__device__ __forceinline__ void gl_lds16(const uint4* g, uint4* l) {
  __builtin_amdgcn_global_load_lds(
      (const __attribute__((address_space(1))) void*)g,
      (__attribute__((address_space(3))) void*)l, 16, 0, 0);
}
// barrier WITHOUT vmcnt drain (staged loads stay in flight; cross-wave traffic is ds_write)
__device__ __forceinline__ void bar_lgkm() {
  asm volatile("s_waitcnt lgkmcnt(0)\ns_barrier" ::: "memory");
}

// ---------- prep: per cell lc (32): 8 q-planes [gate][512] + compact kq=32 tail [gate][128] ----------
__global__ void prepA(const float* __restrict__ W_ih, const float* __restrict__ W_hh,
                      uint4* __restrict__ WB) {
  int idx = blockIdx.x * 256 + threadIdx.x;      // < 32*16896 = 540672
  int lc = idx / 16896;
  int r  = idx % 16896;
  int row, kq;
  if (r < 16384) {
    int q = r >> 11;
    int rem = r & 2047;
    int g = rem >> 9;
    int gt = rem & 511;
    int j = gt >> 2, s = gt & 3;
    kq = s + 4 * q;
    row = g * 128 + j;
  } else {
    int r2 = r - 16384;
    int g = r2 >> 7, j = r2 & 127;
    kq = 32; row = g * 128 + j;
  }
  bool zero = ((lc & 1) && kq == 16);   // cell1: x cols 128..135 are zero-pad
  uint32_t p[4];
#pragma unroll
  for (int i2 = 0; i2 < 4; i2++) {
    float w0 = 0.f, w1 = 0.f;
    if (!zero) {
      int k0 = 8 * kq + 2 * i2;
      w0 = (k0 < 136) ? W_ih[((size_t)lc * 512 + row) * 136 + k0]
                      : W_hh[((size_t)lc * 512 + row) * 128 + (k0 - 136)];
      w1 = (k0 + 1 < 136) ? W_ih[((size_t)lc * 512 + row) * 136 + k0 + 1]
                          : W_hh[((size_t)lc * 512 + row) * 128 + (k0 + 1 - 136)];
    }
    p[i2] = packh2(w0, w1);
  }
  uint4 v; v.x = p[0]; v.y = p[1]; v.z = p[2]; v.w = p[3];
  WB[idx] = v;
}

__global__ void prepB(const float* __restrict__ b_ih, const float* __restrict__ b_hh,
                      const float* __restrict__ W_if, const float* __restrict__ W_fri,
                      const float* __restrict__ W_c1, const float* __restrict__ W_c2,
                      float* __restrict__ bias_comb, uint32_t* __restrict__ Wif16,
                      float* __restrict__ WfriT, float* __restrict__ Wc1T,
                      float* __restrict__ Wc2T) {
  int idx = blockIdx.x * 256 + threadIdx.x;
  if (idx < 16384) { bias_comb[idx] = b_ih[idx] + b_hh[idx]; return; }
  idx -= 16384;
  if (idx < 2560)  {
    int j = idx / 64, k2 = idx % 64;
    Wif16[idx] = packh2(W_if[j * 128 + 2 * k2], W_if[j * 128 + 2 * k2 + 1]);
    return;
  }
  idx -= 2560;
  if (idx < 81920) { int k = idx / 128, j = idx % 128; WfriT[idx] = W_fri[j * 640 + k]; return; }
  idx -= 81920;
  if (idx < 32768) { int k = idx / 128, j = idx % 128; Wc1T[idx]  = W_c1[j * 256 + k]; return; }
  idx -= 32768;
  if (idx < 3840)  { int k = idx / 30,  j = idx % 30;  Wc2T[idx]  = W_c2[j * 128 + k]; return; }
}

// ---------- DNC memory step, 8 lanes (lane = m), single batch; state in registers ----------
__device__ __forceinline__ void memstep_par(
    int m, const float* __restrict__ xi,
    float (&mm)[8], float (&lkr)[8],
    float& u, float& p, float& r, float& w,
    float (&rv)[8]) {
  float rk[8], wk[8], er[8], wv[8];
#pragma unroll
  for (int c = 0; c < 8; c++) {
    rk[c] = tanh_fast(xi[c]);
    wk[c] = tanh_fast(xi[9 + c]);
    er[c] = sigf(xi[18 + c]);
    wv[c] = tanh_fast(xi[26 + c]);
  }
  float rs  = softplus_fast(xi[8]);
  float wsd = softplus_fast(xi[17]);
  float fg  = sigf(xi[34]), ag = sigf(xi[35]), wg = sigf(xi[36]);
  float l0 = xi[37], l1 = xi[38], l2 = xi[39];
  float lmx = fmaxf(l0, fmaxf(l1, l2));
  float eb = __expf(l0 - lmx), ef = __expf(l1 - lmx), ec = __expf(l2 - lmx);
  float minv = rcpf(eb + ef + ec);
  float mode_b = eb * minv, mode_f = ef * minv, mode_c = ec * minv;

  u = u + (1.f - u) * w;
  u *= (1.f - fg * r);

  float kn2 = 0.f, mn2 = 0.f, dp = 0.f;
#pragma unroll
  for (int c = 0; c < 8; c++) { kn2 += wk[c]*wk[c]; mn2 += mm[c]*mm[c]; dp += wk[c]*mm[c]; }
  float sim = dp * rcpf((sqrtf(kn2) + EPSF) * (sqrtf(mn2) + EPSF)) * wsd;
  float mx = sim;
  mx = fmaxf(mx, __shfl_xor(mx, 1));
  mx = fmaxf(mx, __shfl_xor(mx, 2));
  mx = fmaxf(mx, __shfl_xor(mx, 4));
  float e = __expf(sim - mx);
  float se = e;
  se += __shfl_xor(se, 1); se += __shfl_xor(se, 2); se += __shfl_xor(se, 4);
  float wcw = e * rcpf(se);

  float up = EPSF + (1.f - EPSF) * u;
  float prod = 1.f;
#pragma unroll
  for (int n = 0; n < 8; n++) {
    float un = __shfl(up, n);
    bool before = (un < up) || (un == up && n < m);
    prod *= ((n != m) && before) ? un : 1.f;
  }
  float alloc = (1.f - up) * prod;
  float wn = wg * (ag * alloc + (1.f - ag) * wcw);
  float sw = wn;
  sw += __shfl_xor(sw, 1); sw += __shfl_xor(sw, 2); sw += __shfl_xor(sw, 4);

#pragma unroll
  for (int c = 0; c < 8; c++)
    mm[c] = mm[c] * (1.f - wn * er[c]) + wn * wv[c];

  float wnv[8], pvv[8];
#pragma unroll
  for (int n = 0; n < 8; n++) { wnv[n] = __shfl(wn, n); pvv[n] = __shfl(p, n); }
#pragma unroll
  for (int jj = 0; jj < 8; jj++)
    lkr[jj] = (jj == m) ? 0.f : ((1.f - wn - wnv[jj]) * lkr[jj] + wn * pvv[jj]);
  p = (1.f - sw) * p + wn;

  float rn2 = 0.f; mn2 = 0.f; dp = 0.f;
#pragma unroll
  for (int c = 0; c < 8; c++) { rn2 += rk[c]*rk[c]; mn2 += mm[c]*mm[c]; dp += rk[c]*mm[c]; }
  float sim2 = dp * rcpf((sqrtf(rn2) + EPSF) * (sqrtf(mn2) + EPSF)) * rs;
  float mx2 = sim2;
  mx2 = fmaxf(mx2, __shfl_xor(mx2, 1));
  mx2 = fmaxf(mx2, __shfl_xor(mx2, 2));
  mx2 = fmaxf(mx2, __shfl_xor(mx2, 4));
  float e2 = __expf(sim2 - mx2);
  float se2 = e2;
  se2 += __shfl_xor(se2, 1); se2 += __shfl_xor(se2, 2); se2 += __shfl_xor(se2, 4);
  float cw = e2 * rcpf(se2);

  float rv8[8];
#pragma unroll
  for (int n = 0; n < 8; n++) rv8[n] = __shfl(r, n);
  float fwd = 0.f;
#pragma unroll
  for (int jj = 0; jj < 8; jj++) fwd += lkr[jj] * rv8[jj];
  float bw[8];
#pragma unroll
  for (int jj = 0; jj < 8; jj++) bw[jj] = r * lkr[jj];
#pragma unroll
  for (int jj = 0; jj < 8; jj++) {
    bw[jj] += __shfl_xor(bw[jj], 1);
    bw[jj] += __shfl_xor(bw[jj], 2);
    bw[jj] += __shfl_xor(bw[jj], 4);
  }
  bool s1 = (m & 1) != 0, s2 = (m & 2) != 0, s4 = (m & 4) != 0;
  float t0 = s1 ? bw[1] : bw[0];
  float t1 = s1 ? bw[3] : bw[2];
  float t2 = s1 ? bw[5] : bw[4];
  float t3 = s1 ? bw[7] : bw[6];
  float q0 = s2 ? t1 : t0;
  float q1 = s2 ? t3 : t2;
  float bwd = s4 ? q1 : q0;

  float rn = mode_c * cw + mode_f * fwd + mode_b * bwd;

#pragma unroll
  for (int c = 0; c < 8; c++) rv[c] = rn * mm[c];
#pragma unroll
  for (int c = 0; c < 8; c++) {
    rv[c] += __shfl_xor(rv[c], 1);
    rv[c] += __shfl_xor(rv[c], 2);
    rv[c] += __shfl_xor(rv[c], 4);
  }
  r = rn; w = wn;
}

// ---------- aux: xi GEMV from register weights (lanes 0..39), memstep (lanes 0..7) ----------
__device__ __forceinline__ void aux_work(
    int lane, bool write_inp,
    const uint4 (&wreg)[16], const float* __restrict__ b_if,
    const uint4* __restrict__ outhu4, float* __restrict__ xi_lds,
    uint4* __restrict__ inpu4,
    float (&mm)[8], float (&lkr)[8],
    float& u, float& p, float& r, float& w,
    float (&rv)[8]) {
  if (lane < 40) {
    // dual accumulator: halves the serially-dependent fdot2 chain
    float acc0 = 0.f, acc1 = 0.f;
#pragma unroll
    for (int q = 0; q < 8; q++) {
      acc0 = dot8(wreg[2 * q],     outhu4[2 * q],     acc0);
      acc1 = dot8(wreg[2 * q + 1], outhu4[2 * q + 1], acc1);
    }
    xi_lds[lane] = acc0 + acc1 + b_if[lane];
  }
  asm volatile("s_waitcnt lgkmcnt(0)" ::: "memory");
  __builtin_amdgcn_sched_barrier(0);
  __builtin_amdgcn_wave_barrier();
  if (lane < 8) {
    memstep_par(lane, xi_lds, mm, lkr, u, p, r, w, rv);
    if (write_inp && lane == 0) {
      uint4 pv4;
      pv4.x = packh2(rv[0], rv[1]); pv4.y = packh2(rv[2], rv[3]);
      pv4.z = packh2(rv[4], rv[5]); pv4.w = packh2(rv[6], rv[7]);
      inpu4[16] = pv4;
    }
  }
}

// stages one q-plane (4 gate chunks of 1KB) for this wave into buffer bbX
#define STAGE(lcX, qX, bbX)                                                    \
  do {                                                                         \
    const uint4* sp_ = WB + (size_t)(lcX) * 16896 + (size_t)(qX) * 2048 + tid; \
    uint4* dp_ = myslab + (size_t)(bbX) * 256;                                 \
    gl_lds16(sp_,        dp_);                                                 \
    gl_lds16(sp_ + 512,  dp_ + 64);                                            \
    gl_lds16(sp_ + 1024, dp_ + 128);                                           \
    gl_lds16(sp_ + 1536, dp_ + 192);                                           \
  } while (0)

// ---------- main: 128 blocks x 576 threads (waves 0-7 GEMV, wave 8 aux), 1 batch/block ----------
__global__ __launch_bounds__(576) void dnc_main(
    const int* __restrict__ x, const float* __restrict__ embed,
    const uint4* __restrict__ WB, const float* __restrict__ bias_comb,
    const uint32_t* __restrict__ Wif16, const float* __restrict__ b_if,
    const float* __restrict__ W_out, const float* __restrict__ b_out,
    float* __restrict__ y_buf) {
  __shared__ __align__(16) uint16_t hst[32 * 128];       // 8 KB (1 batch)
  __shared__ float c_st[32 * 128];                       // 16 KB
  __shared__ float emb_lds[495];
  __shared__ __align__(16) uint32_t inp16[17 * 4];       // 17 uint4 (136 f16)
  __shared__ __align__(16) uint16_t outh16[128];
  __shared__ float inp_f32[128];
  __shared__ float xi_lds[40];
  __shared__ float rv_f32[8];
  __shared__ __align__(16) uint4 sbuf[8 * 4 * 256];      // 8 waves x 4 bufs x 4KB = 128 KB

  uint4* inpu4 = (uint4*)inp16;
  uint4* hstu4 = (uint4*)hst;
  uint4* outhu4 = (uint4*)outh16;
  uint16_t* inpu16 = (uint16_t*)inp16;

  const int tid = threadIdx.x;
  const int b0 = blockIdx.x;           // one batch per block
  const int ln = tid & 63;
  uint4* myslab = sbuf + (size_t)(tid >> 6) * 1024;

  float mm[8] = {0.f,0.f,0.f,0.f,0.f,0.f,0.f,0.f};
  float lkr[8] = {0.f,0.f,0.f,0.f,0.f,0.f,0.f,0.f};
  float p_u = 0.f, p_p = 0.f, p_r = 0.f, p_w = 0.f;
  float rvout[8];

  // xi GEMV weights in registers (aux lanes 0..39; constant all steps)
  uint4 wreg[16];
  if (tid >= 512 && (tid & 63) < 40) {
    const uint4* wr = (const uint4*)(Wif16 + (tid & 63) * 64);
#pragma unroll
    for (int q = 0; q < 16; q++) wreg[q] = wr[q];
  }

  for (int i = tid; i < 32 * 128; i += 576) { hst[i] = 0; c_st[i] = 0.f; }
  for (int i = tid; i < 495; i += 576) emb_lds[i] = embed[i];
  __syncthreads();
  if (tid < 17) {   // emb for t=0 (slot 16 = zeros)
    int q = tid;
    int ix = x[b0 * TT + 0];
    uint32_t p0, p1, p2, p3;
    {
      int k0 = 8 * q;
      float e0 = (k0 < 15) ? emb_lds[ix * 15 + k0] : 0.f;
      float e1 = (k0 + 1 < 15) ? emb_lds[ix * 15 + k0 + 1] : 0.f;
      float e2 = (k0 + 2 < 15) ? emb_lds[ix * 15 + k0 + 2] : 0.f;
      float e3 = (k0 + 3 < 15) ? emb_lds[ix * 15 + k0 + 3] : 0.f;
      float e4 = (k0 + 4 < 15) ? emb_lds[ix * 15 + k0 + 4] : 0.f;
      float e5 = (k0 + 5 < 15) ? emb_lds[ix * 15 + k0 + 5] : 0.f;
      float e6 = (k0 + 6 < 15) ? emb_lds[ix * 15 + k0 + 6] : 0.f;
      float e7 = (k0 + 7 < 15) ? emb_lds[ix * 15 + k0 + 7] : 0.f;
      p0 = packh2(e0, e1); p1 = packh2(e2, e3); p2 = packh2(e4, e5); p3 = packh2(e6, e7);
    }
    uint4 v; v.x = p0; v.y = p1; v.z = p2; v.w = p3;
    inpu4[q] = v;
  }
  // prologue: stage planes 0,1,2 of (t=0,l=0,cell0) into bufs 0,1,2
  if (tid < 512) { STAGE(0, 0, 0); STAGE(0, 1, 1); STAGE(0, 2, 2); }
  __syncthreads();   // one-time full drain

  for (int t = 0; t < TT; ++t) {
    for (int l = 0; l < LNUM; ++l) {
      const int lc0 = l * 2, lc1 = l * 2 + 1;
      const int nlc0 = (l == 15) ? 0 : lc0 + 2;
      const int j = tid >> 2, s = tid & 3;
      float aA0 = 0.f, aA1 = 0.f, aA2 = 0.f, aA3 = 0.f;
      uint4 wd0 = {}, wd1 = {}, wd2 = {}, wd3 = {};
      float bA0 = 0.f, bA1 = 0.f, bA2 = 0.f, bA3 = 0.f;

      // ===== Phase A: staged GEMV0, 4-buf lookahead-3 (defer kq16) || aux =====
      if (tid < 512) {
        uint4 wt0 = {}, wt1 = {}, wt2 = {}, wt3 = {};
        if (s == 0) {   // kq=32 tail: direct loads (oldest in vmcnt)
          const uint4* wt = WB + (size_t)lc0 * 16896 + 16384 + j;
          wt0 = wt[0]; wt1 = wt[128]; wt2 = wt[256]; wt3 = wt[384];
        }
        if (s == 0) {   // bias hoisted to phase start
          const float* bb = bias_comb + lc0 * 512 + j;
          bA0 = bb[0]; bA1 = bb[128]; bA2 = bb[256]; bA3 = bb[384];
        }
#pragma unroll
        for (int q = 0; q < 8; q++) {
          if (q < 5) STAGE(lc0, q + 3, (q + 3) & 3);
          else       STAGE(lc1, q - 5, (q + 3) & 3);
          asm volatile("s_waitcnt vmcnt(12)" ::: "memory");
          __builtin_amdgcn_sched_barrier(0);
          const uint4* wb = myslab + (size_t)(q & 3) * 256 + ln;
          uint4 w0 = wb[0], w1 = wb[64], w2 = wb[128], w3 = wb[192];
          int kq = s + 4 * q;
          bool defer = (s == 0) && (q == 4);      // kq16 = rv columns, not ready
          int kqe = defer ? 0 : kq;
          const uint4* xp = (kqe < 17) ? (inpu4 + kqe)
                                       : (hstu4 + lc0 * 16 + (kqe - 17));
          uint4 xv0 = *xp;
          if (defer) { wd0 = w0; wd1 = w1; wd2 = w2; wd3 = w3; }
          else {
            aA0 = dot8(w0, xv0, aA0);
            aA1 = dot8(w1, xv0, aA1);
            aA2 = dot8(w2, xv0, aA2);
            aA3 = dot8(w3, xv0, aA3);
          }
        }
        if (s == 0) {   // tail dots (kq=32 -> h(lc0) slice 15)
          uint4 xv0 = hstu4[lc0 * 16 + 15];
          aA0 = dot8(wt0, xv0, aA0);
          aA1 = dot8(wt1, xv0, aA1);
          aA2 = dot8(wt2, xv0, aA2);
          aA3 = dot8(wt3, xv0, aA3);
        }
      } else if (t > 0 || l > 0) {
        const int lane = tid - 512;
        aux_work(lane, /*write_inp=*/(l != 0), wreg, b_if, outhu4, xi_lds,
                 inpu4, mm, lkr, p_u, p_p, p_r, p_w, rvout);
      }
      bar_lgkm();   // B1: rv ready; staged loads stay in flight

      // ===== Phase B: finish kq16 + butterfly reduce + LSTM0 =====
      if (tid < 512) {
        if (s == 0) {
          uint4 xr0 = inpu4[16];
          aA0 = dot8(wd0, xr0, aA0);
          aA1 = dot8(wd1, xr0, aA1);
          aA2 = dot8(wd2, xr0, aA2);
          aA3 = dot8(wd3, xr0, aA3);
        }
        aA0 += __shfl_xor(aA0, 1); aA0 += __shfl_xor(aA0, 2);
        aA1 += __shfl_xor(aA1, 1); aA1 += __shfl_xor(aA1, 2);
        aA2 += __shfl_xor(aA2, 1); aA2 += __shfl_xor(aA2, 2);
        aA3 += __shfl_xor(aA3, 1); aA3 += __shfl_xor(aA3, 2);
        if (s == 0) {
          float gi = aA0 + bA0, gf = aA1 + bA1, gg = aA2 + bA2, go = aA3 + bA3;
          int ci = lc0 * 128 + j;
          float c2 = sigf(gf) * c_st[ci] + sigf(gi) * tanh_fast(gg);
          c_st[ci] = c2;
          hst[ci] = f16bits(sigf(go) * tanh_fast(c2));
        }
      }
      bar_lgkm();   // B2: h0 ready

      // ===== Phase C: staged GEMV1 + reduce + LSTM1 || aux: emb prefetch =====
      if (tid < 512) {
        float cA0 = 0.f, cA1 = 0.f, cA2 = 0.f, cA3 = 0.f;
        uint4 wt0 = {}, wt1 = {}, wt2 = {}, wt3 = {};
        float bC0 = 0.f, bC1 = 0.f, bC2 = 0.f, bC3 = 0.f;
        if (s == 0) {
          const uint4* wt = WB + (size_t)lc1 * 16896 + 16384 + j;
          wt0 = wt[0]; wt1 = wt[128]; wt2 = wt[256]; wt3 = wt[384];
          const float* bb = bias_comb + lc1 * 512 + j;
          bC0 = bb[0]; bC1 = bb[128]; bC2 = bb[256]; bC3 = bb[384];
        }
#pragma unroll
        for (int q = 0; q < 8; q++) {
          if (q < 5) STAGE(lc1, q + 3, (q + 3) & 3);
          else       STAGE(nlc0, q - 5, (q + 3) & 3);
          asm volatile("s_waitcnt vmcnt(12)" ::: "memory");
          __builtin_amdgcn_sched_barrier(0);
          const uint4* wb = myslab + (size_t)(q & 3) * 256 + ln;
          uint4 w0 = wb[0], w1 = wb[64], w2 = wb[128], w3 = wb[192];
          int kq = s + 4 * q;   // kq16 weights are zero (cell1 pad)
          const uint4* xp = (kq < 17) ? (hstu4 + lc0 * 16 + kq)
                                      : (hstu4 + lc1 * 16 + (kq - 17));
          uint4 xv0 = *xp;
          cA0 = dot8(w0, xv0, cA0);
          cA1 = dot8(w1, xv0, cA1);
          cA2 = dot8(w2, xv0, cA2);
          cA3 = dot8(w3, xv0, cA3);
        }
        if (s == 0) {
          uint4 xv0 = hstu4[lc1 * 16 + 15];
          cA0 = dot8(wt0, xv0, cA0);
          cA1 = dot8(wt1, xv0, cA1);
          cA2 = dot8(wt2, xv0, cA2);
          cA3 = dot8(wt3, xv0, cA3);
        }
        cA0 += __shfl_xor(cA0, 1); cA0 += __shfl_xor(cA0, 2);
        cA1 += __shfl_xor(cA1, 1); cA1 += __shfl_xor(cA1, 2);
        cA2 += __shfl_xor(cA2, 1); cA2 += __shfl_xor(cA2, 2);
        cA3 += __shfl_xor(cA3, 1); cA3 += __shfl_xor(cA3, 2);
        if (s == 0) {
          float gi = cA0 + bC0, gf = cA1 + bC1, gg = cA2 + bC2, go = cA3 + bC3;
          int ci = lc1 * 128 + j;
          float c2 = sigf(gf) * c_st[ci] + sigf(gi) * tanh_fast(gg);
          c_st[ci] = c2;
          float h2 = sigf(go) * tanh_fast(c2);   // |h2|<1 -> clip(+-20) no-op
          hst[ci] = f16bits(h2);
          inp_f32[j] = h2;
          outh16[j] = f16bits(h2);
          if (l != 15) inpu16[j] = f16bits(h2);
        }
      } else {
        // aux wave: emb prefetch for t+1 (its x[] vmcnt wait drains only this wave)
        const int lane = tid - 512;
        if (l == 15 && t < 63 && lane < 17) {
          int q = lane;
          int ix = x[b0 * TT + t + 1];
          uint32_t p0, p1, p2, p3;
          {
            int k0 = 8 * q;
            float e0 = (k0 < 15) ? emb_lds[ix * 15 + k0] : 0.f;
            float e1 = (k0 + 1 < 15) ? emb_lds[ix * 15 + k0 + 1] : 0.f;
            float e2 = (k0 + 2 < 15) ? emb_lds[ix * 15 + k0 + 2] : 0.f;
            float e3 = (k0 + 3 < 15) ? emb_lds[ix * 15 + k0 + 3] : 0.f;
            float e4 = (k0 + 4 < 15) ? emb_lds[ix * 15 + k0 + 4] : 0.f;
            float e5 = (k0 + 5 < 15) ? emb_lds[ix * 15 + k0 + 5] : 0.f;
            float e6 = (k0 + 6 < 15) ? emb_lds[ix * 15 + k0 + 6] : 0.f;
            float e7 = (k0 + 7 < 15) ? emb_lds[ix * 15 + k0 + 7] : 0.f;
            p0 = packh2(e0, e1); p1 = packh2(e2, e3); p2 = packh2(e4, e5); p3 = packh2(e6, e7);
          }
          uint4 v; v.x = p0; v.y = p1; v.z = p2; v.w = p3;
          inpu4[q] = v;
        }
      }
      bar_lgkm();   // B3: h1/out ready
    }  // l
  }  // t

  // epilogue: xi + memstep for (t=63, l=15), then y
  if (tid >= 512) {
    const int lane = tid - 512;
    aux_work(lane, /*write_inp=*/false, wreg, b_if, outhu4, xi_lds,
             inpu4, mm, lkr, p_u, p_p, p_r, p_w, rvout);
    if (lane == 0) {
#pragma unroll
      for (int c = 0; c < 8; c++) rv_f32[c] = rvout[c];
    }
  }
  __syncthreads();
  if (tid < 128) {
    int i = tid;
    float a = b_out[i];
    for (int k = 0; k < 128; ++k) a += inp_f32[k] * W_out[i * 136 + k];
    for (int k = 0; k < 8; ++k)   a += rv_f32[k] * W_out[i * 136 + 128 + k];
    y_buf[b0 * H + i] = a;
  }
}

// ---------- output head: 128 blocks (one per batch) x 128 threads ----------
__global__ void head_kernel(const float* __restrict__ y_buf, const float* __restrict__ f,
                            const float* __restrict__ WfriT, const float* __restrict__ b_fri,
                            const float* __restrict__ Wc1T, const float* __restrict__ b_c1,
                            const float* __restrict__ Wc2T, const float* __restrict__ b_c2,
                            float* __restrict__ out) {
  __shared__ float fl[640], yl[128], fo[128], h1l[128];
  int b = blockIdx.x, j = threadIdx.x;
  for (int i = j; i < 640; i += 128) fl[i] = f[b * 640 + i];
  yl[j] = y_buf[b * 128 + j];
  __syncthreads();
  float a = b_fri[j];
  for (int k = 0; k < 640; ++k) a += fl[k] * WfriT[k * 128 + j];
  fo[j] = fmaxf(a, 0.f);
  __syncthreads();
  float a2 = b_c1[j];
  for (int k = 0; k < 128; ++k) a2 += yl[k] * Wc1T[k * 128 + j];
  for (int k = 0; k < 128; ++k) a2 += fo[k] * Wc1T[(128 + k) * 128 + j];
  h1l[j] = fmaxf(a2, 0.f);
  __syncthreads();
  if (j < NCLSN) {
    float a3 = b_c2[j];
    for (int k = 0; k < 128; ++k) a3 += h1l[k] * Wc2T[k * NCLSN + j];
    out[b * NCLSN + j] = a3;
  }
}

extern "C" void kernel_launch(void* const* d_in, const int* in_sizes, int n_in,
                              void* d_out, int out_size, void* d_ws, size_t ws_size,
                              hipStream_t stream) {
  const int*   x     = (const int*)d_in[0];
  const float* f     = (const float*)d_in[1];
  const float* embed = (const float*)d_in[2];
  const float* W_ih  = (const float*)d_in[3];
  const float* W_hh  = (const float*)d_in[4];
  const float* b_ih  = (const float*)d_in[5];
  const float* b_hh  = (const float*)d_in[6];
  const float* W_if  = (const float*)d_in[7];
  const float* b_if  = (const float*)d_in[8];
  const float* W_out = (const float*)d_in[9];
  const float* b_out = (const float*)d_in[10];
  const float* W_fri = (const float*)d_in[11];
  const float* b_fri = (const float*)d_in[12];
  const float* W_c1  = (const float*)d_in[13];
  const float* b_c1  = (const float*)d_in[14];
  const float* W_c2  = (const float*)d_in[15];
  const float* b_c2  = (const float*)d_in[16];

  uint8_t* ws = (uint8_t*)d_ws;
  uint4* WB        = (uint4*)(ws + 0);           // 540672*16 = 8,650,752 B
  float* bias_comb = (float*)(ws + 8650752);     // 65,536 B
  uint32_t* Wif16  = (uint32_t*)(ws + 8716288);  // 10,240 B
  float* WfriT     = (float*)(ws + 8726528);     // 327,680 B
  float* Wc1T      = (float*)(ws + 9054208);     // 131,072 B
  float* Wc2T      = (float*)(ws + 9185280);     // 15,360 B
  float* y_buf     = (float*)(ws + 9200640);     // 65,536 B
  float* out       = (float*)d_out;

  prepA<<<2112, 256, 0, stream>>>(W_ih, W_hh, WB);
  prepB<<<537, 256, 0, stream>>>(b_ih, b_hh, W_if, W_fri, W_c1, W_c2,
                                 bias_comb, Wif16, WfriT, Wc1T, Wc2T);
  dnc_main<<<128, 576, 0, stream>>>(x, embed, WB, bias_comb, Wif16, b_if,
                                    W_out, b_out, y_buf);
  head_kernel<<<128, 128, 0, stream>>>(y_buf, f, WfriT, b_fri, Wc1T, b_c1,
                                       Wc2T, b_c2, out);
}